// Round 2
// baseline (689.897 us; speedup 1.0000x reference)
//
#include <hip/hip_runtime.h>
#include <hip/hip_bf16.h>

typedef __attribute__((ext_vector_type(8))) short bf16x8;
typedef __attribute__((ext_vector_type(4))) float f32x4;
typedef __attribute__((ext_vector_type(4))) short short4v;

static __device__ __forceinline__ short f2bf(float f) {
    __hip_bfloat16 h = __float2bfloat16(f);
    short s; __builtin_memcpy(&s, &h, 2); return s;
}

#define WIN_TOT 65536
#define WN_MASK 4095   // windows per batch - 1 (WN=4096, pow2)
#define SEQ 10
#define EDIM 96
#define DHEAD 24
#define N3 288
#define G 8            // windows per group
#define ROWS 80        // G*SEQ
#define XPITCH 104
#define NGROUPS 8
#define WPB 64         // windows per block
#define NBLOCKS 1024
#define NTHREADS 512

// LDS layout (bytes); all bf16 payloads are short-typed (uniform TBAA class)
#define XO_OFF    0
#define XO_BYTES  (ROWS*XPITCH*2)          // 16640  (X tile, reused as attn_out)
#define Q_OFF     (XO_OFF + XO_BYTES)      // 16640
#define QK_BYTES  (G*4*16*32*2)            // 32768
#define K_OFF     (Q_OFF + QK_BYTES)       // 49408
#define VT_OFF    (K_OFF + QK_BYTES)       // 82176
#define VT_BYTES  (G*4*32*32*2)            // 65536
#define P_OFF     (VT_OFF + VT_BYTES)      // 147712
#define P_BYTES   (8*16*32*2)              // 8192
#define POS_OFF   (P_OFF + P_BYTES)        // 155904
#define POS_BYTES (320)
#define SMEM_BYTES (POS_OFF + POS_BYTES)   // 156224

__global__ __launch_bounds__(NTHREADS, 1)
void swin_msa_fused(const float* __restrict__ X,
                    const float* __restrict__ Wqkv,
                    const float* __restrict__ bqkv,
                    const float* __restrict__ Wo,
                    const float* __restrict__ bo,
                    const float* __restrict__ pos,
                    float* __restrict__ out)
{
    extern __shared__ char smem[];
    short* xo = (short*)(smem + XO_OFF);
    short* qs = (short*)(smem + Q_OFF);
    short* ks = (short*)(smem + K_OFF);
    short* vt = (short*)(smem + VT_OFF);
    short* pb = (short*)(smem + P_OFF);
    float* posf = (float*)(smem + POS_OFF);

    const int tid  = threadIdx.x;
    const int wave = tid >> 6;
    const int lane = tid & 63;
    const int l15  = lane & 15;
    const int quad = lane >> 4;
    const int h    = wave & 3;
    const int k0   = quad * 8;

    // one-time zero of q/k/vT/p buffers (covers all zero-padding regions;
    // live regions are rewritten every group, pad regions never written again)
    {
        uint4* z = (uint4*)(smem + Q_OFF);
        const int n16 = (POS_OFF - Q_OFF) / 16;
        for (int i = tid; i < n16; i += NTHREADS) z[i] = make_uint4(0u,0u,0u,0u);
    }
    for (int i = tid; i < 76; i += NTHREADS) posf[i] = pos[i];

    // persistent W_qkv B-fragments for head h: [part q/k/v][n-tile][k-step]
    bf16x8 bw[3][2][3];
    float biasqkv[3][2];
#pragma unroll
    for (int p = 0; p < 3; ++p)
#pragma unroll
      for (int t = 0; t < 2; ++t) {
        const int d = t*16 + l15;
        const bool valid = d < DHEAD;
        const int ncol = p*EDIM + h*DHEAD + (valid ? d : 0);
        biasqkv[p][t] = valid ? bqkv[ncol] : 0.f;
#pragma unroll
        for (int kk = 0; kk < 3; ++kk) {
          bf16x8 f;
#pragma unroll
          for (int jj = 0; jj < 8; ++jj) {
            const int krow = kk*32 + k0 + jj;
            f[jj] = valid ? f2bf(Wqkv[krow*N3 + ncol]) : (short)0;
          }
          bw[p][t][kk] = f;
        }
      }
    // persistent W_o B-fragments: wave = N-tile (waves 0..5)
    bf16x8 bwo[3];
    float bo_val = 0.f;
    if (wave < 6) {
      const int col = wave*16 + l15;
      bo_val = bo[col];
#pragma unroll
      for (int kk = 0; kk < 3; ++kk) {
        bf16x8 f;
#pragma unroll
        for (int jj = 0; jj < 8; ++jj) {
          const int krow = kk*32 + k0 + jj;
          f[jj] = f2bf(Wo[krow*EDIM + col]);
        }
        bwo[kk] = f;
      }
    }
    __syncthreads();

    const float scale = 0.20412414523193154f;  // 24^-0.5
    const int wb0 = blockIdx.x * WPB;

    for (int g = 0; g < NGROUPS; ++g) {
      const int wbase = wb0 + g*G;
      const long rowbase = (long)wbase * SEQ;

      // ---- stage X: 80 rows x 96 fp32 -> bf16 LDS, pitch 104 ----
      {
        const float4* src = (const float4*)(X + rowbase * (long)EDIM);
        for (int c = tid; c < ROWS*24; c += NTHREADS) {
          float4 v = src[c];
          const int r = c / 24, cc = c - r*24;
          short4v s4 = { f2bf(v.x), f2bf(v.y), f2bf(v.z), f2bf(v.w) };
          *(short4v*)&xo[r*XPITCH + cc*4] = s4;
        }
      }
      __syncthreads();

      // ---- QKV projection: tasks = (m-tile 0..4) x (head 0..3) ----
      for (int task = wave; task < 20; task += 8) {
        const int m = task >> 2;   // task&3 == h by construction (stride 8)
        const bf16x8 a0 = *(const bf16x8*)&xo[(m*16 + l15)*XPITCH +  0 + k0];
        const bf16x8 a1 = *(const bf16x8*)&xo[(m*16 + l15)*XPITCH + 32 + k0];
        const bf16x8 a2 = *(const bf16x8*)&xo[(m*16 + l15)*XPITCH + 64 + k0];
#pragma unroll
        for (int p = 0; p < 3; ++p)
#pragma unroll
          for (int t = 0; t < 2; ++t) {
            f32x4 acc = {0.f,0.f,0.f,0.f};
            acc = __builtin_amdgcn_mfma_f32_16x16x32_bf16(a0, bw[p][t][0], acc, 0,0,0);
            acc = __builtin_amdgcn_mfma_f32_16x16x32_bf16(a1, bw[p][t][1], acc, 0,0,0);
            acc = __builtin_amdgcn_mfma_f32_16x16x32_bf16(a2, bw[p][t][2], acc, 0,0,0);
            const int d = t*16 + l15;
            if (d < DHEAD) {
              const float bias = biasqkv[p][t];
#pragma unroll
              for (int r = 0; r < 4; ++r) {
                const int R = m*16 + quad*4 + r;
                const int w = R / 10, s = R - w*10;
                float v = acc[r] + bias;
                if (p == 0) {
                  v *= scale;
                  qs[((w*4 + h)*16 + s)*32 + d] = f2bf(v);
                } else if (p == 1) {
                  ks[((w*4 + h)*16 + s)*32 + d] = f2bf(v);
                } else {
                  vt[((w*4 + h)*32 + d)*32 + s] = f2bf(v);
                }
              }
            }
          }
      }
      __syncthreads();

      // ---- attention: 32 (window,head) pairs, 4 per wave ----
#pragma unroll
      for (int ii = 0; ii < 4; ++ii) {
        const int pair = wave*4 + ii;
        const int w = pair >> 2, hh = pair & 3;
        const short* qbase = qs + (w*4 + hh)*16*32;
        const short* kbase = ks + (w*4 + hh)*16*32;
        const bf16x8 qf = *(const bf16x8*)&qbase[l15*32 + k0];
        const bf16x8 kf = *(const bf16x8*)&kbase[l15*32 + k0];
        f32x4 sacc = {0.f,0.f,0.f,0.f};
        sacc = __builtin_amdgcn_mfma_f32_16x16x32_bf16(qf, kf, sacc, 0,0,0);
        // shift mask applies to the last window of EACH batch (wn == WN-1)
        const bool islast = ((wbase + w) & WN_MASK) == WN_MASK;
        const int j = l15;
        float pr[4];
#pragma unroll
        for (int r = 0; r < 4; ++r) {
          const int i = quad*4 + r;
          int idx = j - i + 9;
          idx = idx < 0 ? 0 : (idx > 18 ? 18 : idx);
          float sv = sacc[r] + posf[idx*4 + hh];
          if (islast && ((i < 5) != (j < 5))) sv -= 100.f;
          if (j >= 10) sv = -1e30f;
          float mx = sv;
          mx = fmaxf(mx, __shfl_xor(mx, 1, 16));
          mx = fmaxf(mx, __shfl_xor(mx, 2, 16));
          mx = fmaxf(mx, __shfl_xor(mx, 4, 16));
          mx = fmaxf(mx, __shfl_xor(mx, 8, 16));
          float e = __expf(sv - mx);
          float sm = e;
          sm += __shfl_xor(sm, 1, 16);
          sm += __shfl_xor(sm, 2, 16);
          sm += __shfl_xor(sm, 4, 16);
          sm += __shfl_xor(sm, 8, 16);
          pr[r] = e / sm;
        }
        short* pbw = pb + wave*16*32;
#pragma unroll
        for (int r = 0; r < 4; ++r)
          pbw[(quad*4 + r)*32 + j] = f2bf(pr[r]);
        // C-layout -> A-layout round trip. Intra-wave: DS pipe is in-order per
        // wave; fences stop compiler reordering of may-alias LDS accesses.
        asm volatile("" ::: "memory");
        const bf16x8 pf = *(const bf16x8*)&pbw[l15*32 + k0];
        asm volatile("" ::: "memory");
        const short* vbase = vt + (w*4 + hh)*32*32;
#pragma unroll
        for (int t = 0; t < 2; ++t) {
          const bf16x8 vf = *(const bf16x8*)&vbase[(t*16 + l15)*32 + k0];
          f32x4 oacc = {0.f,0.f,0.f,0.f};
          oacc = __builtin_amdgcn_mfma_f32_16x16x32_bf16(pf, vf, oacc, 0,0,0);
          const int d = t*16 + l15;
          if (d < DHEAD) {
#pragma unroll
            for (int r = 0; r < 4; ++r) {
              const int i = quad*4 + r;
              if (i < 10)
                xo[(w*10 + i)*XPITCH + hh*DHEAD + d] = f2bf(oacc[r]);
            }
          }
        }
      }
      __syncthreads();

      // ---- output projection: wave = N-tile (waves 0..5) ----
      if (wave < 6) {
        for (int m = 0; m < 5; ++m) {
          const bf16x8 a0 = *(const bf16x8*)&xo[(m*16 + l15)*XPITCH +  0 + k0];
          const bf16x8 a1 = *(const bf16x8*)&xo[(m*16 + l15)*XPITCH + 32 + k0];
          const bf16x8 a2 = *(const bf16x8*)&xo[(m*16 + l15)*XPITCH + 64 + k0];
          f32x4 acc = {0.f,0.f,0.f,0.f};
          acc = __builtin_amdgcn_mfma_f32_16x16x32_bf16(a0, bwo[0], acc, 0,0,0);
          acc = __builtin_amdgcn_mfma_f32_16x16x32_bf16(a1, bwo[1], acc, 0,0,0);
          acc = __builtin_amdgcn_mfma_f32_16x16x32_bf16(a2, bwo[2], acc, 0,0,0);
          const int col = wave*16 + l15;
#pragma unroll
          for (int r = 0; r < 4; ++r) {
            const int R = m*16 + quad*4 + r;
            out[(rowbase + R)*EDIM + col] = acc[r] + bo_val;
          }
        }
      }
      __syncthreads();
    }
}

extern "C" void kernel_launch(void* const* d_in, const int* in_sizes, int n_in,
                              void* d_out, int out_size, void* d_ws, size_t ws_size,
                              hipStream_t stream) {
    const float* X    = (const float*)d_in[0];
    const float* Wqkv = (const float*)d_in[1];
    const float* bqkv = (const float*)d_in[2];
    const float* Wo   = (const float*)d_in[3];
    const float* bo   = (const float*)d_in[4];
    const float* pos  = (const float*)d_in[5];
    float* out = (float*)d_out;

    (void)hipFuncSetAttribute((const void*)swin_msa_fused,
                              hipFuncAttributeMaxDynamicSharedMemorySize,
                              SMEM_BYTES);
    swin_msa_fused<<<dim3(NBLOCKS), dim3(NTHREADS), SMEM_BYTES, stream>>>(
        X, Wqkv, bqkv, Wo, bo, pos, out);
}